// Round 1
// baseline (220.205 us; speedup 1.0000x reference)
//
#include <hip/hip_runtime.h>

#define BATCHN 32768
#define NLIMB 20

typedef _Float16 h8  __attribute__((ext_vector_type(8)));
typedef _Float16 h4  __attribute__((ext_vector_type(4)));
typedef _Float16 h2v __attribute__((ext_vector_type(2)));
typedef float    f4  __attribute__((ext_vector_type(4)));
typedef unsigned short u16x8 __attribute__((ext_vector_type(8)));
typedef unsigned int   u32x4 __attribute__((ext_vector_type(4)));

// ---- workspace layout (bytes) ----
#define WQ1_OFF 0            // [128][104] f16  (W^T, k<65 else 0)
#define WQ2_OFF 26624        // [128][136] f16
#define WM1_OFF 61440        // [128][72]  f16  (k<33 else 0)
#define WM2_OFF 79872        // [128][136] f16
#define WM3_OFF 114688       // [64][136]  f16  (stays in global, read direct)
#define WLDS_BYTES 114688    // q1,q2,m1,m2 copied to LDS
#define MSG_OFF 132096
#define MSG_SLOT 4718592     // 32768 * 72 * 2 bytes per writer limb (limbs 0..9)
#define XALL_OFF 47318016    // 20 * 32768 f32
// ---- LDS layout ----
#define ABUF_OFF 114688      // activation buffer [128][136] f16
#define LDS_BYTES 149504

// element strides
#define SQ1 104
#define SQ2 136
#define SM1 72
#define SM2 136
#define SM3 136
#define SA  136

#define ABYTE(row,col) (ABUF_OFF + ((((row)*SA) + (col))<<1))
#define MFMA16(a,b,c) __builtin_amdgcn_mfma_f32_16x16x32_f16(a,b,c,0,0,0)

__device__ __forceinline__ float tanh_fast(float v){
  float e = __expf(2.0f*v);
  return 1.0f - 2.0f/(e+1.0f);
}

// ---------------- weight prep: fp32 -> fp16, transpose, pad ----------------
__global__ void critic_prep(const float* __restrict__ qw1, const float* __restrict__ qw2,
                            const float* __restrict__ mw1, const float* __restrict__ mw2,
                            const float* __restrict__ mw3, char* __restrict__ ws)
{
  int i = blockIdx.x*blockDim.x + threadIdx.x;
  int n;
  n = 128*104;
  if (i < n){ int k = i%104;
    ((_Float16*)(ws + WQ1_OFF))[i] = (_Float16)((k<65)? qw1[k*128 + i/104] : 0.0f); return; }
  i -= n; n = 128*136;
  if (i < n){ int k = i%136;
    ((_Float16*)(ws + WQ2_OFF))[i] = (_Float16)((k<128)? qw2[k*128 + i/136] : 0.0f); return; }
  i -= n; n = 128*72;
  if (i < n){ int k = i%72;
    ((_Float16*)(ws + WM1_OFF))[i] = (_Float16)((k<33)? mw1[k*128 + i/72] : 0.0f); return; }
  i -= n; n = 128*136;
  if (i < n){ int k = i%136;
    ((_Float16*)(ws + WM2_OFF))[i] = (_Float16)((k<128)? mw2[k*128 + i/136] : 0.0f); return; }
  i -= n; n = 64*136;
  if (i < n){ int k = i%136;
    ((_Float16*)(ws + WM3_OFF))[i] = (_Float16)((k<128)? mw3[k*64 + i/136] : 0.0f); return; }
}

// ---------------- per-level fused kernel ----------------
// block: 256 thr = 4 waves, each wave owns 32 batch rows; M_block = 128 rows.
// D = W^T x X^T orientation: A-frag = weights (feature in lane&15),
// B-frag = activations row-major [m][k]; batch stays in lane&15 all the way.
__global__ __launch_bounds__(256,1) void critic_level(
    const float* __restrict__ state, const float* __restrict__ action,
    const float* __restrict__ qb1, const float* __restrict__ qb2,
    const float* __restrict__ qw3, const float* __restrict__ qb3,
    const float* __restrict__ mb1, const float* __restrict__ mb2,
    const float* __restrict__ mb3,
    char* __restrict__ ws, int lvl_base, int lvl_cnt)
{
  extern __shared__ char sm[];
  const int tid  = threadIdx.x;
  const int lane = tid & 63;
  const int w    = tid >> 6;       // wave 0..3
  const int g    = lane >> 4;      // lane group 0..3
  const int li   = lane & 15;
  const int m0   = blockIdx.x * 128;
  const int r0   = w * 32;

  // copy prepped weights (q1,q2,m1,m2) into LDS (once per block)
  for (int off = tid*16; off < WLDS_BYTES; off += 4096)
    *(u32x4*)(sm + off) = *(const u32x4*)(ws + off);
  // zero activation buffer once (avoid NaN-pattern garbage in padded K columns)
  for (int off = tid*16; off < 34816; off += 4096)
    *(u32x4*)(sm + ABUF_OFF + off) = (u32x4){0,0,0,0};

  float* xall = (float*)(ws + XALL_OFF);

  for (int limb = lvl_base; limb < lvl_base + lvl_cnt; ++limb) {
    const int parent = (limb-1) >> 1;
    const int cidx   = (limb-1) & 1;
    __syncthreads();   // weights ready / prior limb's abuf reads done

    // ---------- stage xum = [state(32) | act(1) | mi(32) | pad] into abuf ----------
    #pragma unroll
    for (int it=0; it<2; ++it){
      int task = tid + it*256;
      int row = task >> 2, s = task & 3;
      const float* sp = state + (size_t)(m0+row)*640 + limb*32 + s*8;
      f4 va = *(const f4*)sp;
      f4 vb = *(const f4*)(sp+4);
      h8 hv = { (_Float16)va[0],(_Float16)va[1],(_Float16)va[2],(_Float16)va[3],
                (_Float16)vb[0],(_Float16)vb[1],(_Float16)vb[2],(_Float16)vb[3] };
      *(h8*)(sm + ABYTE(row, s*8)) = hv;
    }
    {
      int row = tid >> 1, p = tid & 1;
      int mrow = m0 + row;
      unsigned short e[40] __attribute__((aligned(16)));
      if (limb > 0){
        const unsigned short* msrc =
          (const unsigned short*)(ws + MSG_OFF + (size_t)parent*MSG_SLOT)
          + (size_t)mrow*72 + 32*cidx;
        if (p==0){
          *(u16x8*)&e[0] = *(const u16x8*)&msrc[0];
          *(u16x8*)&e[8] = *(const u16x8*)&msrc[8];
        } else {
          *(u16x8*)&e[8]  = *(const u16x8*)&msrc[8];
          *(u16x8*)&e[16] = *(const u16x8*)&msrc[16];
          *(u16x8*)&e[24] = *(const u16x8*)&msrc[24];
          *(u16x8*)&e[32] = *(const u16x8*)&msrc[32];
        }
      } else {
        #pragma unroll
        for (int j=0;j<40;++j) e[j] = 0;
      }
      if (p==0){
        _Float16 ah = (_Float16)action[(size_t)limb*BATCHN + mrow];
        union { _Float16 h; unsigned short u; } cv; cv.h = ah;
        u16x8 o0 = { cv.u, e[0],e[1],e[2],e[3],e[4],e[5],e[6] };
        u16x8 o1 = { e[7],e[8],e[9],e[10],e[11],e[12],e[13],e[14] };
        *(u16x8*)(sm + ABYTE(row,32)) = o0;
        *(u16x8*)(sm + ABYTE(row,40)) = o1;
      } else {
        u16x8 o0 = { e[15],e[16],e[17],e[18],e[19],e[20],e[21],e[22] };
        u16x8 o1 = { e[23],e[24],e[25],e[26],e[27],e[28],e[29],e[30] };
        u16x8 o2 = { e[31],e[32],e[33],e[34],e[35],e[36],e[37],e[38] };
        *(u16x8*)(sm + ABYTE(row,48)) = o0;
        *(u16x8*)(sm + ABYTE(row,56)) = o1;
        *(u16x8*)(sm + ABYTE(row,64)) = o2;
      }
    }
    __syncthreads();

    // ---------- q-net layer1: h1 = relu(xum @ Wq1 + b1), K=96 ----------
    f4 acc[8][2];
    #pragma unroll
    for (int t=0;t<8;++t){
      f4 bv = *(const f4*)(qb1 + 16*t + 4*g);
      acc[t][0]=bv; acc[t][1]=bv;
    }
    #pragma unroll
    for (int ks=0; ks<3; ++ks){
      h8 bf0 = *(const h8*)(sm + ABYTE(r0+li,    ks*32+8*g));
      h8 bf1 = *(const h8*)(sm + ABYTE(r0+16+li, ks*32+8*g));
      #pragma unroll
      for (int t=0;t<8;++t){
        h8 af = *(const h8*)(sm + WQ1_OFF + (((t*16+li)*SQ1 + ks*32+8*g)<<1));
        acc[t][0] = MFMA16(af, bf0, acc[t][0]);
        acc[t][1] = MFMA16(af, bf1, acc[t][1]);
      }
    }
    // stash mi-region fragments (cols 32.. / 64..) before h1 overwrites them
    h8 st0[2], st1[2];
    #pragma unroll
    for (int bt=0;bt<2;++bt){
      st0[bt] = *(const h8*)(sm + ABYTE(r0+16*bt+li, 32+8*g));
      st1[bt] = *(const h8*)(sm + ABYTE(r0+16*bt+li, 64+8*g));
    }
    // handoff h1 -> abuf rows [m][f] (relu, f16)
    #pragma unroll
    for (int t=0;t<8;++t)
    #pragma unroll
    for (int bt=0;bt<2;++bt){
      f4 v = acc[t][bt];
      h4 hv = { (_Float16)fmaxf(v[0],0.f), (_Float16)fmaxf(v[1],0.f),
                (_Float16)fmaxf(v[2],0.f), (_Float16)fmaxf(v[3],0.f) };
      *(h4*)(sm + ABYTE(r0+16*bt+li, t*16+4*g)) = hv;
    }

    // ---------- q-net layer2: h2 = relu(h1 @ Wq2 + b2), K=128 ----------
    #pragma unroll
    for (int t=0;t<8;++t){
      f4 bv = *(const f4*)(qb2 + 16*t + 4*g);
      acc[t][0]=bv; acc[t][1]=bv;
    }
    #pragma unroll
    for (int ks=0; ks<4; ++ks){
      h8 bf0 = *(const h8*)(sm + ABYTE(r0+li,    ks*32+8*g));
      h8 bf1 = *(const h8*)(sm + ABYTE(r0+16+li, ks*32+8*g));
      #pragma unroll
      for (int t=0;t<8;++t){
        h8 af = *(const h8*)(sm + WQ2_OFF + (((t*16+li)*SQ2 + ks*32+8*g)<<1));
        acc[t][0] = MFMA16(af, bf0, acc[t][0]);
        acc[t][1] = MFMA16(af, bf1, acc[t][1]);
      }
    }
    // ---------- x = relu(h2) . w3 + b3  (VALU dot, keep f32) ----------
    float xs0 = 0.f, xs1 = 0.f;
    #pragma unroll
    for (int t=0;t<8;++t){
      f4 wv = *(const f4*)(qw3 + 16*t + 4*g);
      #pragma unroll
      for (int r=0;r<4;++r){
        xs0 += fmaxf(acc[t][0][r],0.f)*wv[r];
        xs1 += fmaxf(acc[t][1][r],0.f)*wv[r];
      }
    }
    xs0 += __shfl_xor(xs0,16,64); xs0 += __shfl_xor(xs0,32,64);
    xs1 += __shfl_xor(xs1,16,64); xs1 += __shfl_xor(xs1,32,64);
    const float b3 = qb3[0];
    xs0 += b3; xs1 += b3;
    if (g==0){
      xall[(size_t)limb*BATCHN + m0 + r0 + li]      = xs0;
      xall[(size_t)limb*BATCHN + m0 + r0 + 16 + li] = xs1;
    }

    // ---------- message net (non-leaf limbs only) ----------
    if (limb < 10){
      // xm = tanh([x, mi]) fragments (registers; g0 carries x and the k=32 tail)
      h8 xf0[2], xf1[2];
      float xv0 = xs0, xv1 = xs1;
      #pragma unroll
      for (int bt=0;bt<2;++bt){
        h8 s0 = st0[bt];
        if (g==0) s0[0] = (_Float16)(bt ? xv1 : xv0);
        h8 s1 = st1[bt];
        h8 a0, a1;
        #pragma unroll
        for (int j=0;j<8;++j){
          a0[j] = (_Float16)tanh_fast((float)s0[j]);
          a1[j] = (g==0) ? (_Float16)tanh_fast((float)s1[j]) : (_Float16)0.0f;
        }
        xf0[bt]=a0; xf1[bt]=a1;
      }
      // m-net layer1: K=64 (B-frags straight from registers)
      #pragma unroll
      for (int t=0;t<8;++t){
        f4 bv = *(const f4*)(mb1 + 16*t + 4*g);
        acc[t][0]=bv; acc[t][1]=bv;
      }
      #pragma unroll
      for (int ks=0; ks<2; ++ks){
        #pragma unroll
        for (int t=0;t<8;++t){
          h8 af = *(const h8*)(sm + WM1_OFF + (((t*16+li)*SM1 + ks*32+8*g)<<1));
          acc[t][0] = MFMA16(af, ks? xf1[0]:xf0[0], acc[t][0]);
          acc[t][1] = MFMA16(af, ks? xf1[1]:xf0[1], acc[t][1]);
        }
      }
      #pragma unroll
      for (int t=0;t<8;++t)
      #pragma unroll
      for (int bt=0;bt<2;++bt){
        f4 v = acc[t][bt];
        h4 hv = { (_Float16)fmaxf(v[0],0.f), (_Float16)fmaxf(v[1],0.f),
                  (_Float16)fmaxf(v[2],0.f), (_Float16)fmaxf(v[3],0.f) };
        *(h4*)(sm + ABYTE(r0+16*bt+li, t*16+4*g)) = hv;
      }
      // m-net layer2: K=128
      #pragma unroll
      for (int t=0;t<8;++t){
        f4 bv = *(const f4*)(mb2 + 16*t + 4*g);
        acc[t][0]=bv; acc[t][1]=bv;
      }
      #pragma unroll
      for (int ks=0; ks<4; ++ks){
        h8 bf0 = *(const h8*)(sm + ABYTE(r0+li,    ks*32+8*g));
        h8 bf1 = *(const h8*)(sm + ABYTE(r0+16+li, ks*32+8*g));
        #pragma unroll
        for (int t=0;t<8;++t){
          h8 af = *(const h8*)(sm + WM2_OFF + (((t*16+li)*SM2 + ks*32+8*g)<<1));
          acc[t][0] = MFMA16(af, bf0, acc[t][0]);
          acc[t][1] = MFMA16(af, bf1, acc[t][1]);
        }
      }
      #pragma unroll
      for (int t=0;t<8;++t)
      #pragma unroll
      for (int bt=0;bt<2;++bt){
        f4 v = acc[t][bt];
        h4 hv = { (_Float16)fmaxf(v[0],0.f), (_Float16)fmaxf(v[1],0.f),
                  (_Float16)fmaxf(v[2],0.f), (_Float16)fmaxf(v[3],0.f) };
        *(h4*)(sm + ABYTE(r0+16*bt+li, t*16+4*g)) = hv;
      }
      // m-net layer3: 64 features, K=128, A-frags from global (L2-hot)
      const char* wm3 = ws + WM3_OFF;
      f4 accN[4][2];
      #pragma unroll
      for (int t=0;t<4;++t){
        f4 bv = *(const f4*)(mb3 + 16*t + 4*g);
        accN[t][0]=bv; accN[t][1]=bv;
      }
      #pragma unroll
      for (int ks=0; ks<4; ++ks){
        h8 bf0 = *(const h8*)(sm + ABYTE(r0+li,    ks*32+8*g));
        h8 bf1 = *(const h8*)(sm + ABYTE(r0+16+li, ks*32+8*g));
        #pragma unroll
        for (int t=0;t<4;++t){
          h8 af = *(const h8*)(wm3 + (((t*16+li)*SM3 + ks*32+8*g)<<1));
          accN[t][0] = MFMA16(af, bf0, accN[t][0]);
          accN[t][1] = MFMA16(af, bf1, accN[t][1]);
        }
      }
      // l2 norm over 64 features
      float s0=0.f, s1=0.f;
      #pragma unroll
      for (int t=0;t<4;++t)
      #pragma unroll
      for (int r=0;r<4;++r){
        s0 += accN[t][0][r]*accN[t][0][r];
        s1 += accN[t][1][r]*accN[t][1][r];
      }
      s0 += __shfl_xor(s0,16,64); s0 += __shfl_xor(s0,32,64);
      s1 += __shfl_xor(s1,16,64); s1 += __shfl_xor(s1,32,64);
      float inv0 = 1.0f / fmaxf(sqrtf(s0), 1e-12f);
      float inv1 = 1.0f / fmaxf(sqrtf(s1), 1e-12f);
      // store md (fp16) to this limb's message slot
      char* mslot = ws + MSG_OFF + (size_t)limb*MSG_SLOT;
      #pragma unroll
      for (int bt=0;bt<2;++bt){
        float inv = bt ? inv1 : inv0;
        int m = m0 + r0 + 16*bt + li;
        #pragma unroll
        for (int t=0;t<4;++t){
          f4 v = accN[t][bt];
          h2v p0 = { (_Float16)(v[0]*inv), (_Float16)(v[1]*inv) };
          h2v p1 = { (_Float16)(v[2]*inv), (_Float16)(v[3]*inv) };
          *(h2v*)(mslot + (((size_t)m*72 + t*16+4*g)<<1))     = p0;
          *(h2v*)(mslot + (((size_t)m*72 + t*16+4*g + 2)<<1)) = p1;
        }
      }
    }
  }
}

// ---------------- final: out[m] = sum over limbs of x ----------------
__global__ void critic_final(const char* __restrict__ ws, float* __restrict__ out)
{
  int i = blockIdx.x*blockDim.x + threadIdx.x;   // 0..8191, 4 rows each
  const float* xall = (const float*)(ws + XALL_OFF);
  f4 s = {0.f,0.f,0.f,0.f};
  #pragma unroll
  for (int l=0;l<NLIMB;++l)
    s += *(const f4*)(xall + (size_t)l*BATCHN + i*4);
  *(f4*)(out + i*4) = s;
}

extern "C" void kernel_launch(void* const* d_in, const int* in_sizes, int n_in,
                              void* d_out, int out_size, void* d_ws, size_t ws_size,
                              hipStream_t stream) {
  (void)in_sizes; (void)n_in; (void)out_size; (void)ws_size;
  const float* state  = (const float*)d_in[0];
  const float* action = (const float*)d_in[1];
  const float* qw1 = (const float*)d_in[2];
  const float* qb1 = (const float*)d_in[3];
  const float* qw2 = (const float*)d_in[4];
  const float* qb2 = (const float*)d_in[5];
  const float* qw3 = (const float*)d_in[6];
  const float* qb3 = (const float*)d_in[7];
  const float* mw1 = (const float*)d_in[8];
  const float* mb1 = (const float*)d_in[9];
  const float* mw2 = (const float*)d_in[10];
  const float* mb2 = (const float*)d_in[11];
  const float* mw3 = (const float*)d_in[12];
  const float* mb3 = (const float*)d_in[13];
  char* ws = (char*)d_ws;
  float* out = (float*)d_out;

  (void)hipFuncSetAttribute((const void*)critic_level,
                            hipFuncAttributeMaxDynamicSharedMemorySize, LDS_BYTES);

  critic_prep<<<258, 256, 0, stream>>>(qw1,qw2,mw1,mw2,mw3, ws);

  const int lb[5] = {0,1,3,7,15};
  const int lc[5] = {1,2,4,8,5};
  for (int L=0; L<5; ++L)
    critic_level<<<dim3(256), dim3(256), LDS_BYTES, stream>>>(
        state, action, qb1, qb2, qw3, qb3, mb1, mb2, mb3, ws, lb[L], lc[L]);

  critic_final<<<32, 256, 0, stream>>>(ws, out);
}

// Round 2
// 122.895 us; speedup vs baseline: 1.7918x; 1.7918x over previous
//
#include <hip/hip_runtime.h>

#define BATCHN 32768

typedef _Float16 h8  __attribute__((ext_vector_type(8)));
typedef _Float16 h4  __attribute__((ext_vector_type(4)));
typedef float    f4  __attribute__((ext_vector_type(4)));
typedef unsigned int u32x4 __attribute__((ext_vector_type(4)));

// ---- ws layout (f16 elements; byte offset = 2x) ----
// WQ1 [2][128][32]  elem 0      (blk0: qw1 rows 0..31 state; blk1: rows 33..64 mi)
// WQ2 [4][128][32]  elem 8192
// WM1 [2][128][32]  elem 24576  (blk0: mw1 rows 1..32; blk1: kk0=mw1 row0, kk1=mb1)
// WM2 [5][128][32]  elem 32768  (blk4: kk0=mb2)
// WM3 [5][64][32]   elem 53248  (blk4: kk0=mb3)
#define WS_ELEMS 63488

// ---- LDS layout (bytes) ----
#define LM1  0        // [2][128][32] f16 = 16384
#define LM2  16384    // [5][128][32] f16 = 40960
#define ABUF 57344    // [4][128][32] f16 = 32768
#define MSG  90112    // 4 slots x [2][128][32] f16 = 65536
#define LDS_TOTAL 155648

#define MFMA16(a,b,c) __builtin_amdgcn_mfma_f32_16x16x32_f16(a,b,c,0,0,0)

__device__ __forceinline__ float tanh_fast(float v){
  float e = __expf(2.0f*v);
  return 1.0f - 2.0f/(e+1.0f);
}
__device__ __forceinline__ h4 relu4h(f4 v){
  return (h4){ (_Float16)fmaxf(v[0],0.f), (_Float16)fmaxf(v[1],0.f),
               (_Float16)fmaxf(v[2],0.f), (_Float16)fmaxf(v[3],0.f) };
}

// ---------------- weight prep: fp32 -> f16 blocked layouts ----------------
__global__ void critic_prep(const float* __restrict__ qw1, const float* __restrict__ qw2,
                            const float* __restrict__ mw1, const float* __restrict__ mb1,
                            const float* __restrict__ mw2, const float* __restrict__ mb2,
                            const float* __restrict__ mw3, const float* __restrict__ mb3,
                            _Float16* __restrict__ ws)
{
  int i = blockIdx.x*blockDim.x + threadIdx.x;
  if (i < 8192){                                   // WQ1 [2][128][32]
    int ks=i>>12, r=i&4095, f=r>>5, kk=r&31;
    ws[i] = (_Float16)(ks==0 ? qw1[kk*128+f] : qw1[(33+kk)*128+f]);
    return;
  }
  i -= 8192;
  if (i < 16384){                                  // WQ2 [4][128][32]
    int ks=i>>12, r=i&4095, f=r>>5, kk=r&31;
    ws[8192+i] = (_Float16)qw2[(ks*32+kk)*128+f];
    return;
  }
  i -= 16384;
  if (i < 8192){                                   // WM1 [2][128][32]
    int ks=i>>12, r=i&4095, f=r>>5, kk=r&31;
    float v = (ks==0) ? mw1[(1+kk)*128+f]
                      : (kk==0 ? mw1[f] : (kk==1 ? mb1[f] : 0.f));
    ws[24576+i] = (_Float16)v; return;
  }
  i -= 8192;
  if (i < 20480){                                  // WM2 [5][128][32]
    int ks=i>>12, r=i&4095, f=r>>5, kk=r&31;
    float v = (ks<4) ? mw2[(ks*32+kk)*128+f] : (kk==0 ? mb2[f] : 0.f);
    ws[32768+i] = (_Float16)v; return;
  }
  i -= 20480;
  if (i < 10240){                                  // WM3 [5][64][32]
    int ks=i>>11, r=i&2047, f=r>>5, kk=r&31;
    float v = (ks<4) ? mw3[(ks*32+kk)*64+f] : (kk==0 ? mb3[f] : 0.f);
    ws[53248+i] = (_Float16)v; return;
  }
}

// ---------------- single fused kernel: all 20 limbs, DFS order ----------------
// 256 blocks x 256 thr (4 waves). Wave owns 32 batch rows; msgs wave-private in LDS.
// q1/q2 A-fragments persist in registers across all limbs. One barrier total.
__global__ __launch_bounds__(256,1) void critic_all(
    const float* __restrict__ state, const float* __restrict__ action,
    const float* __restrict__ qw1, const float* __restrict__ qb1,
    const float* __restrict__ qb2, const float* __restrict__ qw3,
    const float* __restrict__ qb3,
    const _Float16* __restrict__ ws, float* __restrict__ out)
{
  extern __shared__ char sm[];
  const int tid = threadIdx.x, lane = tid & 63;
  const int w = tid >> 6, g = lane >> 4, li = lane & 15;
  const int rbase = blockIdx.x*128 + w*32;     // wave's 32-row base

  // copy m1,m2 blocked weights into LDS (ws bytes 49152..106496 -> LDS 0..57344)
  for (int off = tid*16; off < 57344; off += 4096)
    *(u32x4*)(sm + off) = *(const u32x4*)((const char*)ws + 49152 + off);
  __syncthreads();   // the only barrier

  // persistent A-fragments: q1 (2 blocks), q2 (4 blocks) -> 192 VGPRs
  h8 aq1[2][8], aq2[4][8];
  #pragma unroll
  for (int ks=0; ks<2; ++ks)
    #pragma unroll
    for (int t=0; t<8; ++t)
      aq1[ks][t] = *(const h8*)(ws + ks*4096 + (16*t+li)*32 + 8*g);
  #pragma unroll
  for (int ks=0; ks<4; ++ks)
    #pragma unroll
    for (int t=0; t<8; ++t)
      aq2[ks][t] = *(const h8*)(ws + 8192 + ks*4096 + (16*t+li)*32 + 8*g);

  const h8 hzero = {};
  h8 conef = hzero; if (g==0) conef[0] = (_Float16)1.0f;   // {1,0,...} bias column
  const f4 z4 = {0.f,0.f,0.f,0.f};
  float xsum0 = 0.f, xsum1 = 0.f;

  // DFS order + depths, packed (5/3 bits per entry)
  const unsigned long long SEQ0 =
    (0ull)|(1ull<<5)|(3ull<<10)|(7ull<<15)|(15ull<<20)|(16ull<<25)|(8ull<<30)|
    (17ull<<35)|(18ull<<40)|(4ull<<45)|(9ull<<50)|(19ull<<55);
  const unsigned long long SEQ1 =
    (10ull)|(2ull<<5)|(5ull<<10)|(11ull<<15)|(12ull<<20)|(6ull<<25)|(13ull<<30)|(14ull<<35);
  const unsigned long long DEPS =
    (0ull)|(1ull<<3)|(2ull<<6)|(3ull<<9)|(4ull<<12)|(4ull<<15)|(3ull<<18)|(4ull<<21)|
    (4ull<<24)|(2ull<<27)|(3ull<<30)|(4ull<<33)|(3ull<<36)|(1ull<<39)|(2ull<<42)|
    (3ull<<45)|(3ull<<48)|(2ull<<51)|(3ull<<54)|(3ull<<57);

  #pragma unroll 1
  for (int i = 0; i < 20; ++i){
    const int limb  = (int)(((i<12) ? (SEQ0>>(5*i)) : (SEQ1>>(5*(i-12)))) & 31);
    const int depth = (int)((DEPS >> (3*i)) & 7);
    const int cidx  = (limb-1) & 1;

    // ---- stage: state -> registers (no LDS), act scalars ----
    h8 bf0[2];
    #pragma unroll
    for (int bt=0; bt<2; ++bt){
      const float* sp = state + (size_t)(rbase+16*bt+li)*640 + limb*32 + 8*g;
      f4 va = *(const f4*)sp, vb = *(const f4*)(sp+4);
      bf0[bt] = (h8){ (_Float16)va[0],(_Float16)va[1],(_Float16)va[2],(_Float16)va[3],
                      (_Float16)vb[0],(_Float16)vb[1],(_Float16)vb[2],(_Float16)vb[3] };
    }
    const float act0 = action[(size_t)limb*BATCHN + rbase + li];
    const float act1 = action[(size_t)limb*BATCHN + rbase + 16 + li];

    // ---- mi fragments from parent msg slot (wave-private rows) ----
    h8 bf1[2];
    if (limb > 0){
      const char* mr = sm + MSG + (depth-1)*16384 + cidx*8192;
      bf1[0] = *(const h8*)(mr + ((w*32+li)*32 + 8*g)*2);
      bf1[1] = *(const h8*)(mr + ((w*32+16+li)*32 + 8*g)*2);
    } else { bf1[0] = hzero; bf1[1] = hzero; }

    // ---- q1: acc = qb1 + act*w1a (VALU rank-1) + state@W + mi@W ----
    f4 acc[8][2];
    #pragma unroll
    for (int t=0; t<8; ++t){
      f4 bv = *(const f4*)(qb1 + 16*t + 4*g);
      f4 wa = *(const f4*)(qw1 + 32*128 + 16*t + 4*g);
      acc[t][0] = bv + act0*wa;
      acc[t][1] = bv + act1*wa;
    }
    #pragma unroll
    for (int t=0; t<8; ++t){
      acc[t][0] = MFMA16(aq1[0][t], bf0[0], acc[t][0]);
      acc[t][1] = MFMA16(aq1[0][t], bf0[1], acc[t][1]);
      acc[t][0] = MFMA16(aq1[1][t], bf1[0], acc[t][0]);
      acc[t][1] = MFMA16(aq1[1][t], bf1[1], acc[t][1]);
    }
    // handoff h1 -> abuf (relu, f16); feature f=16t+4g+r -> blk t>>1, kk=(t&1)*16+4g
    #pragma unroll
    for (int t=0; t<8; ++t)
      #pragma unroll
      for (int bt=0; bt<2; ++bt)
        *(h4*)(sm + ABUF + (((t>>1)*4096 + (w*32+16*bt+li)*32 + (t&1)*16 + 4*g)<<1))
          = relu4h(acc[t][bt]);

    // ---- q2 ----
    #pragma unroll
    for (int t=0; t<8; ++t){
      f4 bv = *(const f4*)(qb2 + 16*t + 4*g);
      acc[t][0] = bv; acc[t][1] = bv;
    }
    #pragma unroll
    for (int ks=0; ks<4; ++ks){
      h8 b0 = *(const h8*)(sm + ABUF + ((ks*4096 + (w*32+li)*32    + 8*g)<<1));
      h8 b1 = *(const h8*)(sm + ABUF + ((ks*4096 + (w*32+16+li)*32 + 8*g)<<1));
      #pragma unroll
      for (int t=0; t<8; ++t){
        acc[t][0] = MFMA16(aq2[ks][t], b0, acc[t][0]);
        acc[t][1] = MFMA16(aq2[ks][t], b1, acc[t][1]);
      }
    }
    // ---- x = relu(h2).w3 + b3 (VALU dot + g-reduce) ----
    float xs0 = 0.f, xs1 = 0.f;
    #pragma unroll
    for (int t=0; t<8; ++t){
      f4 wv = *(const f4*)(qw3 + 16*t + 4*g);
      #pragma unroll
      for (int r=0; r<4; ++r){
        xs0 += fmaxf(acc[t][0][r],0.f)*wv[r];
        xs1 += fmaxf(acc[t][1][r],0.f)*wv[r];
      }
    }
    xs0 += __shfl_xor(xs0,16,64); xs0 += __shfl_xor(xs0,32,64);
    xs1 += __shfl_xor(xs1,16,64); xs1 += __shfl_xor(xs1,32,64);
    const float b3 = qb3[0];
    xs0 += b3; xs1 += b3;
    xsum0 += xs0; xsum1 += xs1;

    // ---- message net (writers: limbs 0..9) ----
    if (limb < 10){
      const float tx0 = tanh_fast(xs0), tx1 = tanh_fast(xs1);
      h8 tf[2];
      #pragma unroll
      for (int bt=0; bt<2; ++bt){
        h8 s = bf1[bt], a;
        #pragma unroll
        for (int j=0; j<8; ++j) a[j] = (_Float16)tanh_fast((float)s[j]);
        tf[bt] = a;
      }
      h8 bx0 = hzero, bx1 = hzero;
      if (g==0){ bx0[0]=(_Float16)tx0; bx0[1]=(_Float16)1.0f;
                 bx1[0]=(_Float16)tx1; bx1[1]=(_Float16)1.0f; }
      // m1: blk0 = mi-weights x tanh(mi); blk1 = [w_x; mb1] x {tx,1}
      #pragma unroll
      for (int t=0; t<8; ++t){
        h8 a0 = *(const h8*)(sm + LM1 + (((16*t+li)*32 + 8*g)<<1));
        h8 a1 = *(const h8*)(sm + LM1 + ((4096 + (16*t+li)*32 + 8*g)<<1));
        acc[t][0] = MFMA16(a1, bx0, z4);
        acc[t][0] = MFMA16(a0, tf[0], acc[t][0]);
        acc[t][1] = MFMA16(a1, bx1, z4);
        acc[t][1] = MFMA16(a0, tf[1], acc[t][1]);
      }
      #pragma unroll
      for (int t=0; t<8; ++t)
        #pragma unroll
        for (int bt=0; bt<2; ++bt)
          *(h4*)(sm + ABUF + (((t>>1)*4096 + (w*32+16*bt+li)*32 + (t&1)*16 + 4*g)<<1))
            = relu4h(acc[t][bt]);
      // m2: 4 blocks + bias block (conef)
      #pragma unroll
      for (int t=0; t<8; ++t){
        h8 ab = *(const h8*)(sm + LM2 + ((4*4096 + (16*t+li)*32 + 8*g)<<1));
        acc[t][0] = MFMA16(ab, conef, z4);
        acc[t][1] = MFMA16(ab, conef, z4);
      }
      #pragma unroll
      for (int ks=0; ks<4; ++ks){
        h8 b0 = *(const h8*)(sm + ABUF + ((ks*4096 + (w*32+li)*32    + 8*g)<<1));
        h8 b1 = *(const h8*)(sm + ABUF + ((ks*4096 + (w*32+16+li)*32 + 8*g)<<1));
        #pragma unroll
        for (int t=0; t<8; ++t){
          h8 a = *(const h8*)(sm + LM2 + ((ks*4096 + (16*t+li)*32 + 8*g)<<1));
          acc[t][0] = MFMA16(a, b0, acc[t][0]);
          acc[t][1] = MFMA16(a, b1, acc[t][1]);
        }
      }
      #pragma unroll
      for (int t=0; t<8; ++t)
        #pragma unroll
        for (int bt=0; bt<2; ++bt)
          *(h4*)(sm + ABUF + (((t>>1)*4096 + (w*32+16*bt+li)*32 + (t&1)*16 + 4*g)<<1))
            = relu4h(acc[t][bt]);
      // m3: 64 feats, A-frags from global (L1-hot), bias block4
      f4 accN[4][2];
      #pragma unroll
      for (int t=0; t<4; ++t){
        h8 ab = *(const h8*)(ws + 53248 + 4*2048 + (16*t+li)*32 + 8*g);
        accN[t][0] = MFMA16(ab, conef, z4);
        accN[t][1] = MFMA16(ab, conef, z4);
      }
      #pragma unroll
      for (int ks=0; ks<4; ++ks){
        h8 b0 = *(const h8*)(sm + ABUF + ((ks*4096 + (w*32+li)*32    + 8*g)<<1));
        h8 b1 = *(const h8*)(sm + ABUF + ((ks*4096 + (w*32+16+li)*32 + 8*g)<<1));
        #pragma unroll
        for (int t=0; t<4; ++t){
          h8 a = *(const h8*)(ws + 53248 + ks*2048 + (16*t+li)*32 + 8*g);
          accN[t][0] = MFMA16(a, b0, accN[t][0]);
          accN[t][1] = MFMA16(a, b1, accN[t][1]);
        }
      }
      // l2 norm + store md to this depth's msg slot (f16)
      float s0=0.f, s1=0.f;
      #pragma unroll
      for (int t=0; t<4; ++t)
        #pragma unroll
        for (int r=0; r<4; ++r){
          s0 += accN[t][0][r]*accN[t][0][r];
          s1 += accN[t][1][r]*accN[t][1][r];
        }
      s0 += __shfl_xor(s0,16,64); s0 += __shfl_xor(s0,32,64);
      s1 += __shfl_xor(s1,16,64); s1 += __shfl_xor(s1,32,64);
      const float inv0 = 1.0f/fmaxf(sqrtf(s0),1e-12f);
      const float inv1 = 1.0f/fmaxf(sqrtf(s1),1e-12f);
      char* mw_ = sm + MSG + depth*16384;
      #pragma unroll
      for (int bt=0; bt<2; ++bt){
        const float inv = bt ? inv1 : inv0;
        const int rb = w*32 + 16*bt + li;
        #pragma unroll
        for (int t=0; t<4; ++t){
          f4 v = accN[t][bt];
          h4 hv = { (_Float16)(v[0]*inv), (_Float16)(v[1]*inv),
                    (_Float16)(v[2]*inv), (_Float16)(v[3]*inv) };
          *(h4*)(mw_ + (((t>>1)*4096 + rb*32 + (t&1)*16 + 4*g)<<1)) = hv;
        }
      }
    }
  }
  if (g==0){
    out[rbase + li]      = xsum0;
    out[rbase + 16 + li] = xsum1;
  }
}

extern "C" void kernel_launch(void* const* d_in, const int* in_sizes, int n_in,
                              void* d_out, int out_size, void* d_ws, size_t ws_size,
                              hipStream_t stream) {
  (void)in_sizes; (void)n_in; (void)out_size; (void)ws_size;
  const float* state  = (const float*)d_in[0];
  const float* action = (const float*)d_in[1];
  const float* qw1 = (const float*)d_in[2];
  const float* qb1 = (const float*)d_in[3];
  const float* qw2 = (const float*)d_in[4];
  const float* qb2 = (const float*)d_in[5];
  const float* qw3 = (const float*)d_in[6];
  const float* qb3 = (const float*)d_in[7];
  const float* mw1 = (const float*)d_in[8];
  const float* mb1 = (const float*)d_in[9];
  const float* mw2 = (const float*)d_in[10];
  const float* mb2 = (const float*)d_in[11];
  const float* mw3 = (const float*)d_in[12];
  const float* mb3 = (const float*)d_in[13];
  _Float16* ws = (_Float16*)d_ws;
  float* out = (float*)d_out;

  (void)hipFuncSetAttribute((const void*)critic_all,
                            hipFuncAttributeMaxDynamicSharedMemorySize, LDS_TOTAL);

  critic_prep<<<248, 256, 0, stream>>>(qw1,qw2,mw1,mb1,mw2,mb2,mw3,mb3, ws);
  critic_all<<<256, 256, LDS_TOTAL, stream>>>(
      state, action, qw1, qb1, qb2, qw3, qb3, ws, out);
}